// Round 1
// baseline (256.646 us; speedup 1.0000x reference)
//
#include <hip/hip_runtime.h>
#include <math.h>

#define D_MODEL 1024
#define D_HEAD  64
#define N_HEADS 16
#define COND_F  768
#define BATCH   2
#define SEQ     2048
#define NTOK    (BATCH*SEQ)      /* 4096 */
#define QKV_N   (3*D_MODEL)      /* 3072 */

typedef unsigned short u16;
typedef __attribute__((ext_vector_type(4))) float  f32x4;
typedef __attribute__((ext_vector_type(8))) __bf16 bfrag;   // MFMA A/B operand (4 VGPRs)
typedef __attribute__((ext_vector_type(4))) unsigned short u16x4;
typedef __attribute__((ext_vector_type(8))) unsigned short u16x8;

__device__ __forceinline__ u16 f2bf(float f) {
    unsigned u = __builtin_bit_cast(unsigned, f);
    return (u16)((u + 0x7fffu + ((u >> 16) & 1u)) >> 16);
}
__device__ __forceinline__ float bf2f(u16 h) {
    unsigned u = ((unsigned)h) << 16;
    return __builtin_bit_cast(float, u);
}

__device__ __forceinline__ void async16(const void* g, void* l) {
    __builtin_amdgcn_global_load_lds(
        (const __attribute__((address_space(1))) unsigned int*)g,
        (__attribute__((address_space(3))) unsigned int*)l, 16, 0, 0);
}

// ---------------------------------------------------------------- cond scale
__global__ __launch_bounds__(256) void cond_kernel(const float* __restrict__ cond,
                                                   const float* __restrict__ w_norm,
                                                   float* __restrict__ cs) {
    int idx = blockIdx.x * 256 + threadIdx.x;       // 0..2047
    int b = idx >> 10, d = idx & 1023;
    const float* c = cond + b * COND_F;
    const float* w = w_norm + (size_t)d * COND_F;
    float acc = 0.f;
    for (int j = 0; j < COND_F; j += 4) {
        float4 cv = *(const float4*)(c + j);
        float4 wv = *(const float4*)(w + j);
        acc += cv.x * wv.x + cv.y * wv.y + cv.z * wv.z + cv.w * wv.w;
    }
    cs[idx] = acc + 1.0f;
}

// ---------------------------------------------------------------- weights -> bf16
__global__ __launch_bounds__(256) void convw_kernel(const float* __restrict__ wqkv,
                                                    const float* __restrict__ wout,
                                                    u16* __restrict__ wqkv_b,
                                                    u16* __restrict__ wout_b) {
    int i = blockIdx.x * 256 + threadIdx.x;         // one per 8 elements
    const int n1 = QKV_N * D_MODEL / 8;             // 393216
    const float* src; u16* dst; int off;
    if (i < n1) { src = wqkv; dst = wqkv_b; off = i * 8; }
    else        { src = wout; dst = wout_b; off = (i - n1) * 8; }
    float4 a = *(const float4*)(src + off);
    float4 b = *(const float4*)(src + off + 4);
    *(u16x4*)(dst + off)     = (u16x4){f2bf(a.x), f2bf(a.y), f2bf(a.z), f2bf(a.w)};
    *(u16x4*)(dst + off + 4) = (u16x4){f2bf(b.x), f2bf(b.y), f2bf(b.z), f2bf(b.w)};
}

// ---------------------------------------------------------------- RMSNorm * cond_scale -> bf16
__global__ __launch_bounds__(256) void rmsnorm_kernel(const float* __restrict__ x,
                                                      const float* __restrict__ cs,
                                                      u16* __restrict__ xn) {
    int tok = blockIdx.x, t = threadIdx.x;
    int b = tok >> 11;
    const float* xr = x + (size_t)tok * D_MODEL;
    float4 v = *(const float4*)(xr + t * 4);
    float ss = v.x * v.x + v.y * v.y + v.z * v.z + v.w * v.w;
    for (int m = 1; m < 64; m <<= 1) ss += __shfl_xor(ss, m);
    __shared__ float red[4];
    int w = t >> 6;
    if ((t & 63) == 0) red[w] = ss;
    __syncthreads();
    float tot = red[0] + red[1] + red[2] + red[3];
    float r = rsqrtf(tot * (1.0f / D_MODEL) + 1e-6f);
    float4 cv = *(const float4*)(cs + b * D_MODEL + t * 4);
    *(u16x4*)(xn + (size_t)tok * D_MODEL + t * 4) =
        (u16x4){f2bf(v.x * cv.x * r), f2bf(v.y * cv.y * r),
                f2bf(v.z * cv.z * r), f2bf(v.w * cv.w * r)};
}

// ---------------------------------------------------------------- 128x128 B^T GEMM (m97 structure)
// C[m,n] = sum_k A[m,k]*B[n,k].  mode 0: scatter bf16 into q/k/v (b,h,s,e).
// mode 1: fp32 out = C + skip.
__global__ __launch_bounds__(256) void gemm_bt(const u16* __restrict__ A, const u16* __restrict__ B,
                                               u16* __restrict__ Cq, u16* __restrict__ Ck,
                                               u16* __restrict__ Cv, float* __restrict__ Cf,
                                               const float* __restrict__ skip,
                                               int M, int N, int K, int mode) {
    __shared__ u16 As[128 * 32];
    __shared__ u16 Bs[128 * 32];
    int tid = threadIdx.x;
    int lane = tid & 63, w = tid >> 6;
    int wr = w >> 1, wc = w & 1;
    int m0 = blockIdx.x * 128, n0 = blockIdx.y * 128;
    f32x4 acc[4][4] = {};
    const u16* Ag = A + (size_t)m0 * K;
    const u16* Bg = B + (size_t)n0 * K;
    int lr = lane & 15, lq = lane >> 4;

    for (int kt = 0; kt < K; kt += 32) {
        __syncthreads();
        #pragma unroll
        for (int i = 0; i < 2; ++i) {
            int c = (i * 4 + w) * 64 + lane;
            int row = c >> 2, col = c & 3;
            async16(Ag + (size_t)row * K + kt + col * 8, &As[(i * 4 + w) * 512]);
            async16(Bg + (size_t)row * K + kt + col * 8, &Bs[(i * 4 + w) * 512]);
        }
        __syncthreads();
        bfrag af[4], bfv[4];
        #pragma unroll
        for (int fm = 0; fm < 4; ++fm)
            af[fm] = *(const bfrag*)&As[(wr * 64 + fm * 16 + lr) * 32 + lq * 8];
        #pragma unroll
        for (int fn = 0; fn < 4; ++fn)
            bfv[fn] = *(const bfrag*)&Bs[(wc * 64 + fn * 16 + lr) * 32 + lq * 8];
        #pragma unroll
        for (int fm = 0; fm < 4; ++fm)
            #pragma unroll
            for (int fn = 0; fn < 4; ++fn)
                acc[fm][fn] = __builtin_amdgcn_mfma_f32_16x16x32_bf16(af[fm], bfv[fn], acc[fm][fn], 0, 0, 0);
    }

    #pragma unroll
    for (int fm = 0; fm < 4; ++fm)
        #pragma unroll
        for (int fn = 0; fn < 4; ++fn)
            #pragma unroll
            for (int r = 0; r < 4; ++r) {
                int row = m0 + wr * 64 + fm * 16 + lq * 4 + r;
                int col = n0 + wc * 64 + fn * 16 + lr;
                float val = acc[fm][fn][r];
                if (mode == 1) {
                    Cf[(size_t)row * N + col] = val + skip[(size_t)row * N + col];
                } else {
                    int sel = col >> 10, h = (col >> 6) & 15, e = col & 63;
                    int bb = row >> 11, s = row & 2047;
                    size_t dst = ((size_t)(bb * N_HEADS + h) * SEQ + s) * D_HEAD + e;
                    u16* p = (sel == 0) ? Cq : ((sel == 1) ? Ck : Cv);
                    p[dst] = f2bf(val);
                }
            }
}

// ---------------------------------------------------------------- q/k: L2-normalize + RoPE (in place)
__global__ __launch_bounds__(256) void postqk_kernel(u16* __restrict__ q, u16* __restrict__ k,
                                                     const float* __restrict__ pos,
                                                     const float* __restrict__ scale) {
    int tid = threadIdx.x, lane = tid & 63, w = tid >> 6;
    int wid = blockIdx.x * 4 + w;            // = bh*2048 + s
    int bh = wid >> 11, s = wid & 2047;
    int b = bh >> 4, h = bh & 15;
    size_t base = (size_t)wid * 64 + lane;
    float qv = bf2f(q[base]);
    float kv = bf2f(k[base]);
    float qs = qv * qv, ks = kv * kv;
    for (int m = 1; m < 64; m <<= 1) { qs += __shfl_xor(qs, m); ks += __shfl_xor(ks, m); }
    float sc = sqrtf(scale[h]);
    qv *= sc * rsqrtf(qs + 1e-6f);
    kv *= sc * rsqrtf(ks + 1e-6f);
    float qp = __shfl_xor(qv, 8);
    float kp = __shfl_xor(kv, 8);
    if (lane < 16) {
        int j = lane & 7;
        // freqs[h][j] = exp(log(pi) + (j*16+h)*ln(10)/128), fp64 to match np
        double lf = 1.1447298858494001741 + (double)(j * 16 + h) * (2.302585092994045684 / 128.0);
        float fr = (float)exp(lf);
        float th = pos[b * SEQ + s] * fr;
        float cth = cosf(th), sth = sinf(th);
        if (lane < 8) { qv = qv * cth - qp * sth; kv = kv * cth - kp * sth; }
        else          { qv = qv * cth + qp * sth; kv = kv * cth + kp * sth; }
    }
    q[base] = f2bf(qv);
    k[base] = f2bf(kv);
}

// ---------------------------------------------------------------- V transpose: (b,h,s,e) -> (b,h,e,s)
__global__ __launch_bounds__(256) void vtrans_kernel(const u16* __restrict__ vraw,
                                                     u16* __restrict__ vt) {
    __shared__ u16 T[64][65];
    int bh = blockIdx.x, st = blockIdx.y;
    int t = threadIdx.x;
    int r = t >> 2, cc = (t & 3) * 16;
    const u16* src = vraw + ((size_t)bh * SEQ + st * 64 + r) * 64 + cc;
    u16x8 a = *(const u16x8*)src;
    u16x8 b2 = *(const u16x8*)(src + 8);
    #pragma unroll
    for (int j = 0; j < 8; ++j) { T[r][cc + j] = a[j]; T[r][cc + 8 + j] = b2[j]; }
    __syncthreads();
    int e = t >> 2, sc = (t & 3) * 16;
    u16x8 o0, o1;
    #pragma unroll
    for (int j = 0; j < 8; ++j) { o0[j] = T[sc + j][e]; o1[j] = T[sc + 8 + j][e]; }
    u16* dst = vt + ((size_t)bh * 64 + e) * SEQ + st * 64 + sc;
    *(u16x8*)dst = o0;
    *(u16x8*)(dst + 8) = o1;
}

// ---------------------------------------------------------------- flash attention
// q,k: (b,h,s,64) bf16 ; vt: (b,h,64,s) bf16 ; o: (b,s,h*64+e) bf16
__global__ __launch_bounds__(256) void attn_kernel(const u16* __restrict__ q,
                                                   const u16* __restrict__ k,
                                                   const u16* __restrict__ vt,
                                                   u16* __restrict__ o) {
    __shared__ u16 Ks[64 * 64];
    __shared__ u16 Vs[64 * 64];
    __shared__ u16 Ps[4][16 * 64];
    int tid = threadIdx.x, lane = tid & 63, w = tid >> 6;
    int bh = blockIdx.y;
    int qs = blockIdx.x * 64;
    int lr = lane & 15, lq = lane >> 4;

    const u16* qb = q + ((size_t)bh * SEQ + qs + w * 16 + lr) * D_HEAD + lq * 8;
    bfrag qf0 = *(const bfrag*)qb;
    bfrag qf1 = *(const bfrag*)(qb + 32);

    f32x4 oacc[4] = {};
    float mrun[4], lrun[4];
    #pragma unroll
    for (int r = 0; r < 4; ++r) { mrun[r] = -1e30f; lrun[r] = 0.f; }

    const u16* kbase = k + (size_t)bh * SEQ * D_HEAD;
    const u16* vbase = vt + (size_t)bh * D_HEAD * SEQ;

    for (int kt = 0; kt < SEQ; kt += 64) {
        __syncthreads();
        #pragma unroll
        for (int i = 0; i < 2; ++i) {
            int c = (i * 4 + w) * 64 + lane;
            int row = c >> 3, col = (c & 7) ^ (row & 7);   // pre-swizzled global source
            async16(kbase + ((size_t)(kt + row)) * 64 + col * 8, &Ks[(i * 4 + w) * 512]);
            async16(vbase + (size_t)row * SEQ + kt + col * 8, &Vs[(i * 4 + w) * 512]);
        }
        __syncthreads();

        f32x4 sacc[4] = {};
        #pragma unroll
        for (int nb = 0; nb < 4; ++nb) {
            int row = lr + nb * 16;
            #pragma unroll
            for (int kb = 0; kb < 2; ++kb) {
                int col16 = lq + kb * 4;
                bfrag kf = *(const bfrag*)&Ks[row * 64 + ((col16 ^ (row & 7)) * 8)];
                sacc[nb] = __builtin_amdgcn_mfma_f32_16x16x32_bf16(kb ? qf1 : qf0, kf, sacc[nb], 0, 0, 0);
            }
        }

        // online softmax in D-layout (row m = lq*4+r, col = lr+16*nb)
        float scl[4];
        #pragma unroll
        for (int r = 0; r < 4; ++r) {
            float mx = fmaxf(fmaxf(sacc[0][r], sacc[1][r]), fmaxf(sacc[2][r], sacc[3][r]));
            mx = fmaxf(mx, __shfl_xor(mx, 1));
            mx = fmaxf(mx, __shfl_xor(mx, 2));
            mx = fmaxf(mx, __shfl_xor(mx, 4));
            mx = fmaxf(mx, __shfl_xor(mx, 8));
            float mnew = fmaxf(mrun[r], mx);
            scl[r] = __expf(mrun[r] - mnew);
            mrun[r] = mnew;
        }
        #pragma unroll
        for (int r = 0; r < 4; ++r) {
            float sum = 0.f;
            int mrow = lq * 4 + r;
            #pragma unroll
            for (int nb = 0; nb < 4; ++nb) {
                float p = __expf(sacc[nb][r] - mrun[r]);
                sum += p;
                int kv = lr + nb * 16;
                Ps[w][mrow * 64 + (((kv >> 3) ^ (mrow & 7)) * 8) + (kv & 7)] = f2bf(p);
            }
            sum += __shfl_xor(sum, 1);
            sum += __shfl_xor(sum, 2);
            sum += __shfl_xor(sum, 4);
            sum += __shfl_xor(sum, 8);
            lrun[r] = lrun[r] * scl[r] + sum;
            oacc[0][r] *= scl[r]; oacc[1][r] *= scl[r];
            oacc[2][r] *= scl[r]; oacc[3][r] *= scl[r];
        }

        // PV
        #pragma unroll
        for (int kb = 0; kb < 2; ++kb) {
            int col16 = lq + kb * 4;
            bfrag pf = *(const bfrag*)&Ps[w][lr * 64 + ((col16 ^ (lr & 7)) * 8)];
            #pragma unroll
            for (int eb = 0; eb < 4; ++eb) {
                int row = lr + eb * 16;
                bfrag vf = *(const bfrag*)&Vs[row * 64 + ((col16 ^ (row & 7)) * 8)];
                oacc[eb] = __builtin_amdgcn_mfma_f32_16x16x32_bf16(pf, vf, oacc[eb], 0, 0, 0);
            }
        }
    }

    int b = bh >> 4, h = bh & 15;
    #pragma unroll
    for (int eb = 0; eb < 4; ++eb)
        #pragma unroll
        for (int r = 0; r < 4; ++r) {
            int qrow = qs + w * 16 + lq * 4 + r;
            int e = lr + eb * 16;
            o[((size_t)b * SEQ + qrow) * D_MODEL + h * D_HEAD + e] = f2bf(oacc[eb][r] / lrun[r]);
        }
}

// ---------------------------------------------------------------- launcher
extern "C" void kernel_launch(void* const* d_in, const int* in_sizes, int n_in,
                              void* d_out, int out_size, void* d_ws, size_t ws_size,
                              hipStream_t stream) {
    const float* x      = (const float*)d_in[0];
    const float* pos    = (const float*)d_in[1];
    const float* cond   = (const float*)d_in[2];
    const float* w_norm = (const float*)d_in[3];
    const float* w_qkv  = (const float*)d_in[4];
    const float* scale  = (const float*)d_in[5];
    const float* w_out  = (const float*)d_in[6];
    float* out = (float*)d_out;

    char* ws = (char*)d_ws;
    u16* xn     = (u16*)ws;                               // 8 MB (aliased by attn_o later)
    u16* wqkv_b = (u16*)(ws + (8u  << 20));               // 6 MB
    u16* wout_b = (u16*)(ws + (14u << 20));               // 2 MB
    float* cs   = (float*)(ws + (16u << 20));             // 8 KB
    u16* qb     = (u16*)(ws + (16u << 20) + (1u << 16));  // 8 MB
    const size_t HSZ = (size_t)BATCH * N_HEADS * SEQ * D_HEAD;
    u16* kb   = qb + HSZ;                                 // 8 MB
    u16* vraw = kb + HSZ;                                 // 8 MB
    u16* vt   = vraw + HSZ;                               // 8 MB
    u16* attn_o = xn;                                     // alias: xn dead after QKV GEMM

    cond_kernel<<<dim3(8), dim3(256), 0, stream>>>(cond, w_norm, cs);
    convw_kernel<<<dim3(2048), dim3(256), 0, stream>>>(w_qkv, w_out, wqkv_b, wout_b);
    rmsnorm_kernel<<<dim3(NTOK), dim3(256), 0, stream>>>(x, cs, xn);
    gemm_bt<<<dim3(NTOK / 128, QKV_N / 128), dim3(256), 0, stream>>>(
        xn, wqkv_b, qb, kb, vraw, (float*)nullptr, (const float*)nullptr,
        NTOK, QKV_N, D_MODEL, 0);
    postqk_kernel<<<dim3(BATCH * N_HEADS * SEQ / 4), dim3(256), 0, stream>>>(qb, kb, pos, scale);
    vtrans_kernel<<<dim3(BATCH * N_HEADS, SEQ / 64), dim3(256), 0, stream>>>(vraw, vt);
    attn_kernel<<<dim3(SEQ / 64, BATCH * N_HEADS), dim3(256), 0, stream>>>(qb, kb, vt, attn_o);
    gemm_bt<<<dim3(NTOK / 128, D_MODEL / 128), dim3(256), 0, stream>>>(
        attn_o, wout_b, nullptr, nullptr, nullptr, out, x,
        NTOK, D_MODEL, D_MODEL, 1);
}

// Round 2
// 207.368 us; speedup vs baseline: 1.2376x; 1.2376x over previous
//
#include <hip/hip_runtime.h>
#include <math.h>

#define D_MODEL 1024
#define D_HEAD  64
#define N_HEADS 16
#define COND_F  768
#define BATCH   2
#define SEQ     2048
#define NTOK    (BATCH*SEQ)      /* 4096 */
#define QKV_N   (3*D_MODEL)      /* 3072 */

typedef unsigned short u16;
typedef __attribute__((ext_vector_type(4))) float  f32x4;
typedef __attribute__((ext_vector_type(8))) __bf16 bfrag;   // MFMA A/B operand (4 VGPRs)
typedef __attribute__((ext_vector_type(4))) __bf16 bf16x4;
typedef __attribute__((ext_vector_type(4))) unsigned short u16x4;
typedef __attribute__((ext_vector_type(8))) unsigned short u16x8;

__device__ __forceinline__ u16 f2bf(float f) {
    unsigned u = __builtin_bit_cast(unsigned, f);
    return (u16)((u + 0x7fffu + ((u >> 16) & 1u)) >> 16);
}
__device__ __forceinline__ float bf2f(u16 h) {
    unsigned u = ((unsigned)h) << 16;
    return __builtin_bit_cast(float, u);
}

__device__ __forceinline__ void async16(const void* g, void* l) {
    __builtin_amdgcn_global_load_lds(
        (const __attribute__((address_space(1))) unsigned int*)g,
        (__attribute__((address_space(3))) unsigned int*)l, 16, 0, 0);
}

// hardware transpose read: within each 16-lane group reading a 128B region,
// lane lr receives column lr of the 4x16 row-major bf16 block (m156/m162).
__device__ __forceinline__ u16x4 tr_read(const u16* p) {
    u16x4 d;
    auto lp = (const __attribute__((address_space(3))) u16*)p;
    asm volatile("ds_read_b64_tr_b16 %0, %1" : "=v"(d) : "v"(lp) : "memory");
    return d;
}

// ---------------------------------------------------------------- prep: weights->bf16 + cond scale
__global__ __launch_bounds__(256) void prep_kernel(const float* __restrict__ wqkv,
                                                   const float* __restrict__ wout,
                                                   u16* __restrict__ wqkv_b,
                                                   u16* __restrict__ wout_b,
                                                   const float* __restrict__ cond,
                                                   const float* __restrict__ w_norm,
                                                   float* __restrict__ cs) {
    if (blockIdx.x < 2048) {
        int i = blockIdx.x * 256 + threadIdx.x;       // one per 8 elements
        const int n1 = QKV_N * D_MODEL / 8;           // 393216
        const float* src; u16* dst; int off;
        if (i < n1) { src = wqkv; dst = wqkv_b; off = i * 8; }
        else        { src = wout; dst = wout_b; off = (i - n1) * 8; }
        float4 a = *(const float4*)(src + off);
        float4 b = *(const float4*)(src + off + 4);
        *(u16x4*)(dst + off)     = (u16x4){f2bf(a.x), f2bf(a.y), f2bf(a.z), f2bf(a.w)};
        *(u16x4*)(dst + off + 4) = (u16x4){f2bf(b.x), f2bf(b.y), f2bf(b.z), f2bf(b.w)};
    } else {
        int idx = (blockIdx.x - 2048) * 256 + threadIdx.x;   // 0..2047
        int b = idx >> 10, d = idx & 1023;
        const float* c = cond + b * COND_F;
        const float* w = w_norm + (size_t)d * COND_F;
        float acc = 0.f;
        for (int j = 0; j < COND_F; j += 4) {
            float4 cv = *(const float4*)(c + j);
            float4 wv = *(const float4*)(w + j);
            acc += cv.x * wv.x + cv.y * wv.y + cv.z * wv.z + cv.w * wv.w;
        }
        cs[idx] = acc + 1.0f;
    }
}

// ---------------------------------------------------------------- RMSNorm * cond_scale -> bf16
__global__ __launch_bounds__(256) void rmsnorm_kernel(const float* __restrict__ x,
                                                      const float* __restrict__ cs,
                                                      u16* __restrict__ xn) {
    int tok = blockIdx.x, t = threadIdx.x;
    int b = tok >> 11;
    const float* xr = x + (size_t)tok * D_MODEL;
    float4 v = *(const float4*)(xr + t * 4);
    float ss = v.x * v.x + v.y * v.y + v.z * v.z + v.w * v.w;
    for (int m = 1; m < 64; m <<= 1) ss += __shfl_xor(ss, m);
    __shared__ float red[4];
    int w = t >> 6;
    if ((t & 63) == 0) red[w] = ss;
    __syncthreads();
    float tot = red[0] + red[1] + red[2] + red[3];
    float r = rsqrtf(tot * (1.0f / D_MODEL) + 1e-6f);
    float4 cv = *(const float4*)(cs + b * D_MODEL + t * 4);
    *(u16x4*)(xn + (size_t)tok * D_MODEL + t * 4) =
        (u16x4){f2bf(v.x * cv.x * r), f2bf(v.y * cv.y * r),
                f2bf(v.z * cv.z * r), f2bf(v.w * cv.w * r)};
}

// ---------------------------------------------------------------- 128x128 B^T GEMM (m97 structure)
// C[m,n] = sum_k A[m,k]*B[n,k].  mode 0: scatter bf16 into q/k (b,h,s,e), v -> vt (b,h,e,s).
// mode 1: fp32 out = C + skip.
__global__ __launch_bounds__(256) void gemm_bt(const u16* __restrict__ A, const u16* __restrict__ B,
                                               u16* __restrict__ Cq, u16* __restrict__ Ck,
                                               u16* __restrict__ Cv, float* __restrict__ Cf,
                                               const float* __restrict__ skip,
                                               int M, int N, int K, int mode) {
    __shared__ u16 As[128 * 32];
    __shared__ u16 Bs[128 * 32];
    int tid = threadIdx.x;
    int lane = tid & 63, w = tid >> 6;
    int wr = w >> 1, wc = w & 1;
    int m0 = blockIdx.x * 128, n0 = blockIdx.y * 128;
    f32x4 acc[4][4] = {};
    const u16* Ag = A + (size_t)m0 * K;
    const u16* Bg = B + (size_t)n0 * K;
    int lr = lane & 15, lq = lane >> 4;

    for (int kt = 0; kt < K; kt += 32) {
        __syncthreads();
        #pragma unroll
        for (int i = 0; i < 2; ++i) {
            int c = (i * 4 + w) * 64 + lane;
            int row = c >> 2, col = c & 3;
            async16(Ag + (size_t)row * K + kt + col * 8, &As[(i * 4 + w) * 512]);
            async16(Bg + (size_t)row * K + kt + col * 8, &Bs[(i * 4 + w) * 512]);
        }
        __syncthreads();
        bfrag af[4], bfv[4];
        #pragma unroll
        for (int fm = 0; fm < 4; ++fm)
            af[fm] = *(const bfrag*)&As[(wr * 64 + fm * 16 + lr) * 32 + lq * 8];
        #pragma unroll
        for (int fn = 0; fn < 4; ++fn)
            bfv[fn] = *(const bfrag*)&Bs[(wc * 64 + fn * 16 + lr) * 32 + lq * 8];
        #pragma unroll
        for (int fm = 0; fm < 4; ++fm)
            #pragma unroll
            for (int fn = 0; fn < 4; ++fn)
                acc[fm][fn] = __builtin_amdgcn_mfma_f32_16x16x32_bf16(af[fm], bfv[fn], acc[fm][fn], 0, 0, 0);
    }

    #pragma unroll
    for (int fm = 0; fm < 4; ++fm)
        #pragma unroll
        for (int fn = 0; fn < 4; ++fn) {
            int rowbase = m0 + wr * 64 + fm * 16 + lq * 4;
            int colbase = n0 + wc * 64 + fn * 16;          // lane-invariant
            if (mode == 1) {
                #pragma unroll
                for (int r = 0; r < 4; ++r) {
                    int row = rowbase + r, col = colbase + lr;
                    Cf[(size_t)row * N + col] = acc[fm][fn][r] + skip[(size_t)row * N + col];
                }
            } else {
                int sel = colbase >> 10;
                int h = (colbase >> 6) & 15;
                int bb = rowbase >> 11, s = rowbase & 2047;
                if (sel == 2) {
                    int e = (colbase & 63) + lr;
                    u16x4 pk = {f2bf(acc[fm][fn][0]), f2bf(acc[fm][fn][1]),
                                f2bf(acc[fm][fn][2]), f2bf(acc[fm][fn][3])};
                    *(u16x4*)&Cv[((size_t)(bb * N_HEADS + h) * D_HEAD + e) * SEQ + s] = pk;
                } else {
                    int e = (colbase & 63) + lr;
                    u16* p = sel ? Ck : Cq;
                    #pragma unroll
                    for (int r = 0; r < 4; ++r)
                        p[((size_t)(bb * N_HEADS + h) * SEQ + (s + r)) * D_HEAD + e] = f2bf(acc[fm][fn][r]);
                }
            }
        }
}

// ---------------------------------------------------------------- q/k: L2-normalize + RoPE (in place)
__global__ __launch_bounds__(256) void postqk_kernel(u16* __restrict__ q, u16* __restrict__ k,
                                                     const float* __restrict__ pos,
                                                     const float* __restrict__ scale) {
    int tid = threadIdx.x, lane = tid & 63, w = tid >> 6;
    int wid = blockIdx.x * 4 + w;            // = bh*2048 + s
    int bh = wid >> 11, s = wid & 2047;
    int b = bh >> 4, h = bh & 15;
    size_t base = (size_t)wid * 64 + lane;
    float qv = bf2f(q[base]);
    float kv = bf2f(k[base]);
    float qs = qv * qv, ks = kv * kv;
    for (int m = 1; m < 64; m <<= 1) { qs += __shfl_xor(qs, m); ks += __shfl_xor(ks, m); }
    float sc = sqrtf(scale[h]);
    qv *= sc * rsqrtf(qs + 1e-6f);
    kv *= sc * rsqrtf(ks + 1e-6f);
    float qp = __shfl_xor(qv, 8);
    float kp = __shfl_xor(kv, 8);
    if (lane < 16) {
        int j = lane & 7;
        // freqs[h][j] = exp(log(pi) + (j*16+h)*ln(10)/128), fp64 to match np
        double lf = 1.1447298858494001741 + (double)(j * 16 + h) * (2.302585092994045684 / 128.0);
        float fr = (float)exp(lf);
        float th = pos[b * SEQ + s] * fr;
        float cth = cosf(th), sth = sinf(th);
        if (lane < 8) { qv = qv * cth - qp * sth; kv = kv * cth - kp * sth; }
        else          { qv = qv * cth + qp * sth; kv = kv * cth + kp * sth; }
    }
    q[base] = f2bf(qv);
    k[base] = f2bf(kv);
}

// ---------------------------------------------------------------- flash attention (fixed max = 10)
// q,k: (b,h,s,64) bf16 ; vt: (b,h,64,s) bf16 ; o: (b,s,h*64+e) bf16
// 4 waves x 32 q-rows = QBLK 128. Scores bounded by sqrt(10)*sqrt(10)=10 (cosine
// similarity of L2-normalized q,k) -> fixed softmax max, no online rescaling.
__global__ __launch_bounds__(256) void attn_kernel(const u16* __restrict__ q,
                                                   const u16* __restrict__ k,
                                                   const u16* __restrict__ vt,
                                                   u16* __restrict__ o) {
    __shared__ u16 Ks[64 * 64];
    __shared__ u16 Vs[64 * 64];
    __shared__ u16 Ps[4][2][64 * 16];   // per-wave, per-mfrag col-major P plane [k=64][q=16]
    int tid = threadIdx.x, lane = tid & 63, w = tid >> 6;
    int bh = blockIdx.y;
    int qs = blockIdx.x * 128;
    int lr = lane & 15, lq = lane >> 4;

    bfrag qf[2][2];
    #pragma unroll
    for (int mf = 0; mf < 2; ++mf) {
        const u16* qb = q + ((size_t)bh * SEQ + qs + w * 32 + mf * 16 + lr) * D_HEAD + lq * 8;
        qf[mf][0] = *(const bfrag*)qb;
        qf[mf][1] = *(const bfrag*)(qb + 32);
    }

    f32x4 oacc[2][4] = {};
    float lsum[2][4] = {};
    const u16* kbase = k + (size_t)bh * SEQ * D_HEAD;
    const u16* vbase = vt + (size_t)bh * D_HEAD * SEQ;
    u16* Pw = &Ps[w][0][0];

    const float L2E = 1.4426950408889634f;
    const float BIAS = 14.426950408889634f;   // 10 * log2(e)

    for (int kt = 0; kt < SEQ; kt += 64) {
        __syncthreads();
        #pragma unroll
        for (int i = 0; i < 2; ++i) {
            int c = (i * 4 + w) * 64 + lane;
            int row = c >> 3, col = (c & 7) ^ (row & 7);   // pre-swizzled global source
            async16(kbase + ((size_t)(kt + row)) * 64 + col * 8, &Ks[(i * 4 + w) * 512]);
            async16(vbase + (size_t)row * SEQ + kt + col * 8, &Vs[(i * 4 + w) * 512]);
        }
        __syncthreads();

        // QK^T: D[i=q(16 of mf)][j=kv16(nb)] ; kf reused across both m-frags
        f32x4 sacc[2][4] = {};
        #pragma unroll
        for (int nb = 0; nb < 4; ++nb) {
            int row = nb * 16 + lr;
            #pragma unroll
            for (int kb = 0; kb < 2; ++kb) {
                bfrag kf = *(const bfrag*)&Ks[row * 64 + (((kb * 4 + lq) ^ (row & 7)) * 8)];
                sacc[0][nb] = __builtin_amdgcn_mfma_f32_16x16x32_bf16(qf[0][kb], kf, sacc[0][nb], 0, 0, 0);
                sacc[1][nb] = __builtin_amdgcn_mfma_f32_16x16x32_bf16(qf[1][kb], kf, sacc[1][nb], 0, 0, 0);
            }
        }

        // P = exp(s - 10); accumulate lane-local sums; store col-major (packed b64)
        #pragma unroll
        for (int mf = 0; mf < 2; ++mf)
            #pragma unroll
            for (int nb = 0; nb < 4; ++nb) {
                float p0 = exp2f(sacc[mf][nb][0] * L2E - BIAS);
                float p1 = exp2f(sacc[mf][nb][1] * L2E - BIAS);
                float p2 = exp2f(sacc[mf][nb][2] * L2E - BIAS);
                float p3 = exp2f(sacc[mf][nb][3] * L2E - BIAS);
                lsum[mf][0] += p0; lsum[mf][1] += p1;
                lsum[mf][2] += p2; lsum[mf][3] += p3;
                bf16x4 pk = {(__bf16)p0, (__bf16)p1, (__bf16)p2, (__bf16)p3};
                *(bf16x4*)&Pw[mf * 1024 + (nb * 16 + lr) * 16 + lq * 4] = pk;
            }

        // transpose-read P back as PV A-fragments: lane needs P[q=lr][k=kb*32+lq*8+j]
        u16x4 pa[2][2][2];
        #pragma unroll
        for (int mf = 0; mf < 2; ++mf)
            #pragma unroll
            for (int kb = 0; kb < 2; ++kb) {
                const u16* pbase = &Pw[mf * 1024 + kb * 512 + lq * 128 + lr * 4];
                pa[mf][kb][0] = tr_read(pbase);
                pa[mf][kb][1] = tr_read(pbase + 64);
            }
        asm volatile("s_waitcnt lgkmcnt(0)" ::: "memory");
        __builtin_amdgcn_sched_barrier(0);

        // PV: D[i=q][j=e16(eb)] ; vf reused across both m-frags
        #pragma unroll
        for (int kb = 0; kb < 2; ++kb) {
            bfrag pf[2];
            #pragma unroll
            for (int mf = 0; mf < 2; ++mf) {
                u16x8 cat = __builtin_shufflevector(pa[mf][kb][0], pa[mf][kb][1], 0, 1, 2, 3, 4, 5, 6, 7);
                pf[mf] = __builtin_bit_cast(bfrag, cat);
            }
            #pragma unroll
            for (int eb = 0; eb < 4; ++eb) {
                int row = eb * 16 + lr;
                bfrag vf = *(const bfrag*)&Vs[row * 64 + (((kb * 4 + lq) ^ (row & 7)) * 8)];
                oacc[0][eb] = __builtin_amdgcn_mfma_f32_16x16x32_bf16(pf[0], vf, oacc[0][eb], 0, 0, 0);
                oacc[1][eb] = __builtin_amdgcn_mfma_f32_16x16x32_bf16(pf[1], vf, oacc[1][eb], 0, 0, 0);
            }
        }
    }

    int b = bh >> 4, h = bh & 15;
    #pragma unroll
    for (int mf = 0; mf < 2; ++mf)
        #pragma unroll
        for (int r = 0; r < 4; ++r) {
            float s = lsum[mf][r];
            s += __shfl_xor(s, 1); s += __shfl_xor(s, 2);
            s += __shfl_xor(s, 4); s += __shfl_xor(s, 8);
            float inv = 1.0f / s;
            int qrow = qs + w * 32 + mf * 16 + lq * 4 + r;
            #pragma unroll
            for (int eb = 0; eb < 4; ++eb) {
                int e = eb * 16 + lr;
                o[((size_t)b * SEQ + qrow) * D_MODEL + h * D_HEAD + e] = f2bf(oacc[mf][eb][r] * inv);
            }
        }
}

// ---------------------------------------------------------------- launcher
extern "C" void kernel_launch(void* const* d_in, const int* in_sizes, int n_in,
                              void* d_out, int out_size, void* d_ws, size_t ws_size,
                              hipStream_t stream) {
    const float* x      = (const float*)d_in[0];
    const float* pos    = (const float*)d_in[1];
    const float* cond   = (const float*)d_in[2];
    const float* w_norm = (const float*)d_in[3];
    const float* w_qkv  = (const float*)d_in[4];
    const float* scale  = (const float*)d_in[5];
    const float* w_out  = (const float*)d_in[6];
    float* out = (float*)d_out;

    char* ws = (char*)d_ws;
    u16* xn     = (u16*)ws;                               // 8 MB (aliased by attn_o later)
    u16* wqkv_b = (u16*)(ws + (8u  << 20));               // 6 MB
    u16* wout_b = (u16*)(ws + (14u << 20));               // 2 MB
    float* cs   = (float*)(ws + (16u << 20));             // 8 KB
    u16* qb     = (u16*)(ws + (16u << 20) + (1u << 16));  // 8 MB
    const size_t HSZ = (size_t)BATCH * N_HEADS * SEQ * D_HEAD;
    u16* kb = qb + HSZ;                                   // 8 MB
    u16* vt = kb + HSZ;                                   // 8 MB (written transposed by gemm)
    u16* attn_o = xn;                                     // alias: xn dead after QKV GEMM

    prep_kernel<<<dim3(2056), dim3(256), 0, stream>>>(w_qkv, w_out, wqkv_b, wout_b, cond, w_norm, cs);
    rmsnorm_kernel<<<dim3(NTOK), dim3(256), 0, stream>>>(x, cs, xn);
    gemm_bt<<<dim3(NTOK / 128, QKV_N / 128), dim3(256), 0, stream>>>(
        xn, wqkv_b, qb, kb, vt, (float*)nullptr, (const float*)nullptr,
        NTOK, QKV_N, D_MODEL, 0);
    postqk_kernel<<<dim3(BATCH * N_HEADS * SEQ / 4), dim3(256), 0, stream>>>(qb, kb, pos, scale);
    attn_kernel<<<dim3(SEQ / 128, BATCH * N_HEADS), dim3(256), 0, stream>>>(qb, kb, vt, attn_o);
    gemm_bt<<<dim3(NTOK / 128, D_MODEL / 128), dim3(256), 0, stream>>>(
        attn_o, wout_b, nullptr, nullptr, nullptr, out, x,
        NTOK, D_MODEL, D_MODEL, 1);
}

// Round 3
// 170.069 us; speedup vs baseline: 1.5091x; 1.2193x over previous
//
#include <hip/hip_runtime.h>
#include <math.h>

#define D_MODEL 1024
#define D_HEAD  64
#define N_HEADS 16
#define COND_F  768
#define BATCH   2
#define SEQ     2048
#define NTOK    (BATCH*SEQ)      /* 4096 */
#define QKV_N   (3*D_MODEL)      /* 3072 */

typedef unsigned short u16;
typedef __attribute__((ext_vector_type(4))) float  f32x4;
typedef __attribute__((ext_vector_type(8))) __bf16 bfrag;   // MFMA A/B operand (4 VGPRs)
typedef __attribute__((ext_vector_type(4))) __bf16 bf16x4;
typedef __attribute__((ext_vector_type(4))) unsigned short u16x4;
typedef __attribute__((ext_vector_type(8))) unsigned short u16x8;

__device__ __forceinline__ u16 f2bf(float f) {
    unsigned u = __builtin_bit_cast(unsigned, f);
    return (u16)((u + 0x7fffu + ((u >> 16) & 1u)) >> 16);
}
__device__ __forceinline__ float bf2f(u16 h) {
    unsigned u = ((unsigned)h) << 16;
    return __builtin_bit_cast(float, u);
}

__device__ __forceinline__ void async16(const void* g, void* l) {
    __builtin_amdgcn_global_load_lds(
        (const __attribute__((address_space(1))) unsigned int*)g,
        (__attribute__((address_space(3))) unsigned int*)l, 16, 0, 0);
}

__device__ __forceinline__ u16x4 tr_read(const u16* p) {
    u16x4 d;
    auto lp = (const __attribute__((address_space(3))) u16*)p;
    asm volatile("ds_read_b64_tr_b16 %0, %1" : "=v"(d) : "v"(lp) : "memory");
    return d;
}

// ---------------------------------------------------------------- prep: weights->bf16 + cond scale
__global__ __launch_bounds__(256) void prep_kernel(const float* __restrict__ wqkv,
                                                   const float* __restrict__ wout,
                                                   u16* __restrict__ wqkv_b,
                                                   u16* __restrict__ wout_b,
                                                   const float* __restrict__ cond,
                                                   const float* __restrict__ w_norm,
                                                   float* __restrict__ cs) {
    if (blockIdx.x < 2048) {
        int i = blockIdx.x * 256 + threadIdx.x;       // one per 8 elements
        const int n1 = QKV_N * D_MODEL / 8;           // 393216
        const float* src; u16* dst; int off;
        if (i < n1) { src = wqkv; dst = wqkv_b; off = i * 8; }
        else        { src = wout; dst = wout_b; off = (i - n1) * 8; }
        float4 a = *(const float4*)(src + off);
        float4 b = *(const float4*)(src + off + 4);
        *(u16x4*)(dst + off)     = (u16x4){f2bf(a.x), f2bf(a.y), f2bf(a.z), f2bf(a.w)};
        *(u16x4*)(dst + off + 4) = (u16x4){f2bf(b.x), f2bf(b.y), f2bf(b.z), f2bf(b.w)};
    } else {
        // one wave per output element (b,d)
        int lane = threadIdx.x & 63, w = threadIdx.x >> 6;
        int wid = (blockIdx.x - 2048) * 4 + w;        // 0..2047
        int b = wid >> 10, d = wid & 1023;
        const float* c = cond + b * COND_F;
        const float* wn = w_norm + (size_t)d * COND_F;
        float acc = 0.f;
        #pragma unroll
        for (int kk = 0; kk < 3; ++kk) {
            int j = kk * 256 + lane * 4;
            float4 cv = *(const float4*)(c + j);
            float4 wv = *(const float4*)(wn + j);
            acc += cv.x * wv.x + cv.y * wv.y + cv.z * wv.z + cv.w * wv.w;
        }
        for (int m = 1; m < 64; m <<= 1) acc += __shfl_xor(acc, m);
        if (lane == 0) cs[wid] = acc + 1.0f;
    }
}

// ---------------------------------------------------------------- RMSNorm * cond_scale -> bf16
__global__ __launch_bounds__(256) void rmsnorm_kernel(const float* __restrict__ x,
                                                      const float* __restrict__ cs,
                                                      u16* __restrict__ xn) {
    int tok = blockIdx.x, t = threadIdx.x;
    int b = tok >> 11;
    const float* xr = x + (size_t)tok * D_MODEL;
    float4 v = *(const float4*)(xr + t * 4);
    float ss = v.x * v.x + v.y * v.y + v.z * v.z + v.w * v.w;
    for (int m = 1; m < 64; m <<= 1) ss += __shfl_xor(ss, m);
    __shared__ float red[4];
    int w = t >> 6;
    if ((t & 63) == 0) red[w] = ss;
    __syncthreads();
    float tot = red[0] + red[1] + red[2] + red[3];
    float r = rsqrtf(tot * (1.0f / D_MODEL) + 1e-6f);
    float4 cv = *(const float4*)(cs + b * D_MODEL + t * 4);
    *(u16x4*)(xn + (size_t)tok * D_MODEL + t * 4) =
        (u16x4){f2bf(v.x * cv.x * r), f2bf(v.y * cv.y * r),
                f2bf(v.z * cv.z * r), f2bf(v.w * cv.w * r)};
}

// ---------------------------------------------------------------- tiled B^T GEMM (m97 structure)
// C[m,n] = sum_k A[m,k]*B[n,k].  MODE 0 (NT=128): scatter bf16 into q/k (b,h,s,e), v -> vt (b,h,e,s).
// MODE 1: fp32 out = C + skip.  Tile: 128 x NT.
template<int NT, int MODE>
__global__ __launch_bounds__(256) void gemm_bt(const u16* __restrict__ A, const u16* __restrict__ B,
                                               u16* __restrict__ Cq, u16* __restrict__ Ck,
                                               u16* __restrict__ Cv, float* __restrict__ Cf,
                                               const float* __restrict__ skip,
                                               int M, int N, int K) {
    __shared__ u16 As[128 * 32];
    __shared__ u16 Bs[NT * 32];
    constexpr int FN = NT / 32;                       // col frags per warp (128->4, 64->2)
    int tid = threadIdx.x;
    int lane = tid & 63, w = tid >> 6;
    int wr = (NT == 128) ? (w >> 1) : (w >> 1);
    int wc = w & 1;
    int m0 = blockIdx.x * 128, n0 = blockIdx.y * NT;
    f32x4 acc[4][FN] = {};
    const u16* Ag = A + (size_t)m0 * K;
    const u16* Bg = B + (size_t)n0 * K;
    int lr = lane & 15, lq = lane >> 4;

    for (int kt = 0; kt < K; kt += 32) {
        __syncthreads();
        #pragma unroll
        for (int i = 0; i < 2; ++i) {
            int c = i * 256 + tid;
            int row = c >> 2, col = c & 3;
            async16(Ag + (size_t)row * K + kt + col * 8, &As[c * 8]);
        }
        #pragma unroll
        for (int i = 0; i < NT / 64; ++i) {
            int c = i * 256 + tid;
            int row = c >> 2, col = c & 3;
            async16(Bg + (size_t)row * K + kt + col * 8, &Bs[c * 8]);
        }
        __syncthreads();
        bfrag af[4], bfv[FN];
        #pragma unroll
        for (int fm = 0; fm < 4; ++fm)
            af[fm] = *(const bfrag*)&As[(wr * 64 + fm * 16 + lr) * 32 + lq * 8];
        #pragma unroll
        for (int fn = 0; fn < FN; ++fn)
            bfv[fn] = *(const bfrag*)&Bs[(wc * (NT / 2) + fn * 16 + lr) * 32 + lq * 8];
        #pragma unroll
        for (int fm = 0; fm < 4; ++fm)
            #pragma unroll
            for (int fn = 0; fn < FN; ++fn)
                acc[fm][fn] = __builtin_amdgcn_mfma_f32_16x16x32_bf16(af[fm], bfv[fn], acc[fm][fn], 0, 0, 0);
    }

    #pragma unroll
    for (int fm = 0; fm < 4; ++fm)
        #pragma unroll
        for (int fn = 0; fn < FN; ++fn) {
            int rowbase = m0 + wr * 64 + fm * 16 + lq * 4;
            int colbase = n0 + wc * (NT / 2) + fn * 16;        // lane-invariant
            if (MODE == 1) {
                #pragma unroll
                for (int r = 0; r < 4; ++r) {
                    int row = rowbase + r, col = colbase + lr;
                    Cf[(size_t)row * N + col] = acc[fm][fn][r] + skip[(size_t)row * N + col];
                }
            } else {
                int sel = colbase >> 10;
                int h = (colbase >> 6) & 15;
                int bb = rowbase >> 11, s = rowbase & 2047;
                if (sel == 2) {
                    int e = (colbase & 63) + lr;
                    u16x4 pk = {f2bf(acc[fm][fn][0]), f2bf(acc[fm][fn][1]),
                                f2bf(acc[fm][fn][2]), f2bf(acc[fm][fn][3])};
                    *(u16x4*)&Cv[((size_t)(bb * N_HEADS + h) * D_HEAD + e) * SEQ + s] = pk;
                } else {
                    int e = (colbase & 63) + lr;
                    u16* p = sel ? Ck : Cq;
                    #pragma unroll
                    for (int r = 0; r < 4; ++r)
                        p[((size_t)(bb * N_HEADS + h) * SEQ + (s + r)) * D_HEAD + e] = f2bf(acc[fm][fn][r]);
                }
            }
        }
}

// ---------------------------------------------------------------- q/k: L2-normalize + RoPE (in place)
// q additionally pre-scaled by log2(e) so attention uses bare exp2.
__global__ __launch_bounds__(256) void postqk_kernel(u16* __restrict__ q, u16* __restrict__ k,
                                                     const float* __restrict__ pos,
                                                     const float* __restrict__ scale) {
    int tid = threadIdx.x, lane = tid & 63, w = tid >> 6;
    int wid = blockIdx.x * 4 + w;            // = bh*2048 + s
    int bh = wid >> 11, s = wid & 2047;
    int b = bh >> 4, h = bh & 15;
    size_t base = (size_t)wid * 64 + lane;
    float qv = bf2f(q[base]);
    float kv = bf2f(k[base]);
    float qs = qv * qv, ks = kv * kv;
    for (int m = 1; m < 64; m <<= 1) { qs += __shfl_xor(qs, m); ks += __shfl_xor(ks, m); }
    float sc = sqrtf(scale[h]);
    qv *= sc * 1.4426950408889634f * rsqrtf(qs + 1e-6f);   // fold log2(e) into q
    kv *= sc * rsqrtf(ks + 1e-6f);
    float qp = __shfl_xor(qv, 8);
    float kp = __shfl_xor(kv, 8);
    if (lane < 16) {
        int j = lane & 7;
        // freqs[h][j] = exp(log(pi) + (j*16+h)*ln(10)/128), fp64 to match np
        double lf = 1.1447298858494001741 + (double)(j * 16 + h) * (2.302585092994045684 / 128.0);
        float fr = (float)exp(lf);
        float th = pos[b * SEQ + s] * fr;
        float cth = cosf(th), sth = sinf(th);
        if (lane < 8) { qv = qv * cth - qp * sth; kv = kv * cth - kp * sth; }
        else          { qv = qv * cth + qp * sth; kv = kv * cth + kp * sth; }
    }
    q[base] = f2bf(qv);
    k[base] = f2bf(kv);
}

// ---------------------------------------------------------------- flash attention, split-KV
// q,k: (b,h,s,64) bf16 (q pre-scaled by log2e); vt: (b,h,64,s) bf16
// Each block: 128 q-rows x 1024 kv (z = blockIdx.z). P = exp2(s), no max subtraction
// (scores bounded: |s| <= 10*log2e). Row-sums via ones-B MFMA into oacc5.
__global__ __launch_bounds__(256) void attn_kernel(const u16* __restrict__ q,
                                                   const u16* __restrict__ k,
                                                   const u16* __restrict__ vt,
                                                   u16* __restrict__ o_part,
                                                   float* __restrict__ lsum_part) {
    __shared__ u16 Ks[64 * 64];
    __shared__ u16 Vs[64 * 64];
    __shared__ u16 Ps[4][2][64 * 16];   // per-wave, per-mfrag col-major P plane [k=64][q=16]
    int tid = threadIdx.x, lane = tid & 63, w = tid >> 6;
    int bh = blockIdx.y;
    int qs = blockIdx.x * 128;
    int z = blockIdx.z;
    int kv0 = z * (SEQ / 2);
    int lr = lane & 15, lq = lane >> 4;

    bfrag qf[2][2];
    #pragma unroll
    for (int mf = 0; mf < 2; ++mf) {
        const u16* qb = q + ((size_t)bh * SEQ + qs + w * 32 + mf * 16 + lr) * D_HEAD + lq * 8;
        qf[mf][0] = *(const bfrag*)qb;
        qf[mf][1] = *(const bfrag*)(qb + 32);
    }
    bfrag ones;
    #pragma unroll
    for (int j = 0; j < 8; ++j) ones[j] = (__bf16)1.0f;

    f32x4 oacc[2][4] = {};
    f32x4 oacc5[2] = {};                 // row sums
    const u16* kbase = k + (size_t)bh * SEQ * D_HEAD;
    const u16* vbase = vt + (size_t)bh * D_HEAD * SEQ;
    u16* Pw = &Ps[w][0][0];

    for (int kt = kv0; kt < kv0 + SEQ / 2; kt += 64) {
        __syncthreads();
        #pragma unroll
        for (int i = 0; i < 2; ++i) {
            int c = (i * 4 + w) * 64 + lane;
            int row = c >> 3, col = (c & 7) ^ (row & 7);   // pre-swizzled global source
            async16(kbase + ((size_t)(kt + row)) * 64 + col * 8, &Ks[(i * 4 + w) * 512]);
            async16(vbase + (size_t)row * SEQ + kt + col * 8, &Vs[(i * 4 + w) * 512]);
        }
        __syncthreads();

        // QK^T: D[i=q(16 of mf)][j=kv16(nb)] ; kf reused across both m-frags
        f32x4 sacc[2][4] = {};
        #pragma unroll
        for (int nb = 0; nb < 4; ++nb) {
            int row = nb * 16 + lr;
            #pragma unroll
            for (int kb = 0; kb < 2; ++kb) {
                bfrag kf = *(const bfrag*)&Ks[row * 64 + (((kb * 4 + lq) ^ (row & 7)) * 8)];
                sacc[0][nb] = __builtin_amdgcn_mfma_f32_16x16x32_bf16(qf[0][kb], kf, sacc[0][nb], 0, 0, 0);
                sacc[1][nb] = __builtin_amdgcn_mfma_f32_16x16x32_bf16(qf[1][kb], kf, sacc[1][nb], 0, 0, 0);
            }
        }

        // P = exp2(s); store col-major (packed b64)
        #pragma unroll
        for (int mf = 0; mf < 2; ++mf)
            #pragma unroll
            for (int nb = 0; nb < 4; ++nb) {
                float p0 = exp2f(sacc[mf][nb][0]);
                float p1 = exp2f(sacc[mf][nb][1]);
                float p2 = exp2f(sacc[mf][nb][2]);
                float p3 = exp2f(sacc[mf][nb][3]);
                bf16x4 pk = {(__bf16)p0, (__bf16)p1, (__bf16)p2, (__bf16)p3};
                *(bf16x4*)&Pw[mf * 1024 + (nb * 16 + lr) * 16 + lq * 4] = pk;
            }

        // transpose-read P back as PV A-fragments: lane needs P[q=lr][k=kb*32+lq*8+j]
        u16x4 pa[2][2][2];
        #pragma unroll
        for (int mf = 0; mf < 2; ++mf)
            #pragma unroll
            for (int kb = 0; kb < 2; ++kb) {
                const u16* pbase = &Pw[mf * 1024 + kb * 512 + lq * 128 + lr * 4];
                pa[mf][kb][0] = tr_read(pbase);
                pa[mf][kb][1] = tr_read(pbase + 64);
            }
        asm volatile("s_waitcnt lgkmcnt(0)" ::: "memory");
        __builtin_amdgcn_sched_barrier(0);

        // PV: D[i=q][j=e16(eb)] ; vf reused across both m-frags; +ones MFMA for row sums
        #pragma unroll
        for (int kb = 0; kb < 2; ++kb) {
            bfrag pf[2];
            #pragma unroll
            for (int mf = 0; mf < 2; ++mf) {
                u16x8 cat = __builtin_shufflevector(pa[mf][kb][0], pa[mf][kb][1], 0, 1, 2, 3, 4, 5, 6, 7);
                pf[mf] = __builtin_bit_cast(bfrag, cat);
            }
            oacc5[0] = __builtin_amdgcn_mfma_f32_16x16x32_bf16(pf[0], ones, oacc5[0], 0, 0, 0);
            oacc5[1] = __builtin_amdgcn_mfma_f32_16x16x32_bf16(pf[1], ones, oacc5[1], 0, 0, 0);
            #pragma unroll
            for (int eb = 0; eb < 4; ++eb) {
                int row = eb * 16 + lr;
                bfrag vf = *(const bfrag*)&Vs[row * 64 + (((kb * 4 + lq) ^ (row & 7)) * 8)];
                oacc[0][eb] = __builtin_amdgcn_mfma_f32_16x16x32_bf16(pf[0], vf, oacc[0][eb], 0, 0, 0);
                oacc[1][eb] = __builtin_amdgcn_mfma_f32_16x16x32_bf16(pf[1], vf, oacc[1][eb], 0, 0, 0);
            }
        }
    }

    int b = bh >> 4, h = bh & 15;
    u16* op = o_part + (size_t)z * NTOK * D_MODEL;
    #pragma unroll
    for (int mf = 0; mf < 2; ++mf) {
        #pragma unroll
        for (int r = 0; r < 4; ++r) {
            int qrow = qs + w * 32 + mf * 16 + lq * 4 + r;
            if (lr == 0)
                lsum_part[((size_t)z * BATCH * N_HEADS + bh) * SEQ + qrow] = oacc5[mf][r];
            #pragma unroll
            for (int eb = 0; eb < 4; ++eb) {
                int e = eb * 16 + lr;
                op[((size_t)b * SEQ + qrow) * D_MODEL + h * D_HEAD + e] = f2bf(oacc[mf][eb][r]);
            }
        }
    }
}

// ---------------------------------------------------------------- combine split-KV partials
__global__ __launch_bounds__(256) void combine_kernel(const u16* __restrict__ o_part,
                                                      const float* __restrict__ lsum_part,
                                                      u16* __restrict__ out) {
    int i = blockIdx.x * 256 + threadIdx.x;      // one per 8 elements
    int base = i * 8;
    int t = base >> 10, col = base & 1023;
    int b = t >> 11, s = t & 2047, h = col >> 6;
    size_t li = (size_t)(b * N_HEADS + h) * SEQ + s;
    float inv = 1.0f / (lsum_part[li] + lsum_part[li + (size_t)BATCH * N_HEADS * SEQ]);
    u16x8 a0 = *(const u16x8*)(o_part + base);
    u16x8 a1 = *(const u16x8*)(o_part + (size_t)NTOK * D_MODEL + base);
    u16x8 r;
    #pragma unroll
    for (int j = 0; j < 8; ++j) r[j] = f2bf((bf2f(a0[j]) + bf2f(a1[j])) * inv);
    *(u16x8*)(out + base) = r;
}

// ---------------------------------------------------------------- launcher
extern "C" void kernel_launch(void* const* d_in, const int* in_sizes, int n_in,
                              void* d_out, int out_size, void* d_ws, size_t ws_size,
                              hipStream_t stream) {
    const float* x      = (const float*)d_in[0];
    const float* pos    = (const float*)d_in[1];
    const float* cond   = (const float*)d_in[2];
    const float* w_norm = (const float*)d_in[3];
    const float* w_qkv  = (const float*)d_in[4];
    const float* scale  = (const float*)d_in[5];
    const float* w_out  = (const float*)d_in[6];
    float* out = (float*)d_out;

    char* ws = (char*)d_ws;
    u16* xn     = (u16*)ws;                               // 8 MB (aliased by attn_o later)
    u16* wqkv_b = (u16*)(ws + (8u  << 20));               // 6 MB
    u16* wout_b = (u16*)(ws + (14u << 20));               // 2 MB
    float* cs   = (float*)(ws + (16u << 20));             // 8 KB
    u16* qb     = (u16*)(ws + (16u << 20) + (1u << 16));  // 8 MB
    const size_t HSZ = (size_t)BATCH * N_HEADS * SEQ * D_HEAD;
    u16* kb = qb + HSZ;                                   // 8 MB
    u16* vt = kb + HSZ;                                   // 8 MB (written transposed by gemm)
    u16* o_part   = (u16*)(ws + (41u << 20));             // 2 x 8 MB bf16 partials
    float* lsum_p = (float*)(ws + (57u << 20));           // 2 x 256 KB
    u16* attn_o = xn;                                     // alias: xn dead after QKV GEMM

    prep_kernel<<<dim3(2560), dim3(256), 0, stream>>>(w_qkv, w_out, wqkv_b, wout_b, cond, w_norm, cs);
    rmsnorm_kernel<<<dim3(NTOK), dim3(256), 0, stream>>>(x, cs, xn);
    gemm_bt<128, 0><<<dim3(NTOK / 128, QKV_N / 128), dim3(256), 0, stream>>>(
        xn, wqkv_b, qb, kb, vt, (float*)nullptr, (const float*)nullptr,
        NTOK, QKV_N, D_MODEL);
    postqk_kernel<<<dim3(BATCH * N_HEADS * SEQ / 4), dim3(256), 0, stream>>>(qb, kb, pos, scale);
    attn_kernel<<<dim3(SEQ / 128, BATCH * N_HEADS, 2), dim3(256), 0, stream>>>(
        qb, kb, vt, o_part, lsum_p);
    combine_kernel<<<dim3(NTOK * D_MODEL / 8 / 256), dim3(256), 0, stream>>>(o_part, lsum_p, attn_o);
    gemm_bt<64, 1><<<dim3(NTOK / 128, D_MODEL / 64), dim3(256), 0, stream>>>(
        attn_o, wout_b, nullptr, nullptr, nullptr, out, x,
        NTOK, D_MODEL, D_MODEL);
}

// Round 4
// 157.925 us; speedup vs baseline: 1.6251x; 1.0769x over previous
//
#include <hip/hip_runtime.h>
#include <math.h>

#define D_MODEL 1024
#define D_HEAD  64
#define N_HEADS 16
#define COND_F  768
#define BATCH   2
#define SEQ     2048
#define NTOK    (BATCH*SEQ)      /* 4096 */
#define QKV_N   (3*D_MODEL)      /* 3072 */

typedef unsigned short u16;
typedef __attribute__((ext_vector_type(4))) float  f32x4;
typedef __attribute__((ext_vector_type(8))) __bf16 bfrag;   // MFMA A/B operand (4 VGPRs)
typedef __attribute__((ext_vector_type(4))) __bf16 bf16x4;
typedef __attribute__((ext_vector_type(4))) unsigned short u16x4;
typedef __attribute__((ext_vector_type(8))) unsigned short u16x8;

__device__ __forceinline__ u16 f2bf(float f) {
    unsigned u = __builtin_bit_cast(unsigned, f);
    return (u16)((u + 0x7fffu + ((u >> 16) & 1u)) >> 16);
}
__device__ __forceinline__ float bf2f(u16 h) {
    unsigned u = ((unsigned)h) << 16;
    return __builtin_bit_cast(float, u);
}

__device__ __forceinline__ void async16(const void* g, void* l) {
    __builtin_amdgcn_global_load_lds(
        (const __attribute__((address_space(1))) unsigned int*)g,
        (__attribute__((address_space(3))) unsigned int*)l, 16, 0, 0);
}

__device__ __forceinline__ u16x4 tr_read(const u16* p) {
    u16x4 d;
    auto lp = (const __attribute__((address_space(3))) u16*)p;
    asm volatile("ds_read_b64_tr_b16 %0, %1" : "=v"(d) : "v"(lp) : "memory");
    return d;
}

// ---------------------------------------------------------------- prep: weights->bf16 + cond scale
__global__ __launch_bounds__(256) void prep_kernel(const float* __restrict__ wqkv,
                                                   const float* __restrict__ wout,
                                                   u16* __restrict__ wqkv_b,
                                                   u16* __restrict__ wout_b,
                                                   const float* __restrict__ cond,
                                                   const float* __restrict__ w_norm,
                                                   float* __restrict__ cs) {
    if (blockIdx.x < 2048) {
        int i = blockIdx.x * 256 + threadIdx.x;       // one per 8 elements
        const int n1 = QKV_N * D_MODEL / 8;           // 393216
        const float* src; u16* dst; int off;
        if (i < n1) { src = wqkv; dst = wqkv_b; off = i * 8; }
        else        { src = wout; dst = wout_b; off = (i - n1) * 8; }
        float4 a = *(const float4*)(src + off);
        float4 b = *(const float4*)(src + off + 4);
        *(u16x4*)(dst + off)     = (u16x4){f2bf(a.x), f2bf(a.y), f2bf(a.z), f2bf(a.w)};
        *(u16x4*)(dst + off + 4) = (u16x4){f2bf(b.x), f2bf(b.y), f2bf(b.z), f2bf(b.w)};
    } else {
        // one wave per output element (b,d)
        int lane = threadIdx.x & 63, w = threadIdx.x >> 6;
        int wid = (blockIdx.x - 2048) * 4 + w;        // 0..2047
        int b = wid >> 10, d = wid & 1023;
        const float* c = cond + b * COND_F;
        const float* wn = w_norm + (size_t)d * COND_F;
        float acc = 0.f;
        #pragma unroll
        for (int kk = 0; kk < 3; ++kk) {
            int j = kk * 256 + lane * 4;
            float4 cv = *(const float4*)(c + j);
            float4 wv = *(const float4*)(wn + j);
            acc += cv.x * wv.x + cv.y * wv.y + cv.z * wv.z + cv.w * wv.w;
        }
        for (int m = 1; m < 64; m <<= 1) acc += __shfl_xor(acc, m);
        if (lane == 0) cs[wid] = acc + 1.0f;
    }
}

// ---------------------------------------------------------------- RMSNorm * cond_scale -> bf16
__global__ __launch_bounds__(256) void rmsnorm_kernel(const float* __restrict__ x,
                                                      const float* __restrict__ cs,
                                                      u16* __restrict__ xn) {
    int tok = blockIdx.x, t = threadIdx.x;
    int b = tok >> 11;
    const float* xr = x + (size_t)tok * D_MODEL;
    float4 v = *(const float4*)(xr + t * 4);
    float ss = v.x * v.x + v.y * v.y + v.z * v.z + v.w * v.w;
    for (int m = 1; m < 64; m <<= 1) ss += __shfl_xor(ss, m);
    __shared__ float red[4];
    int w = t >> 6;
    if ((t & 63) == 0) red[w] = ss;
    __syncthreads();
    float tot = red[0] + red[1] + red[2] + red[3];
    float r = rsqrtf(tot * (1.0f / D_MODEL) + 1e-6f);
    float4 cv = *(const float4*)(cs + b * D_MODEL + t * 4);
    *(u16x4*)(xn + (size_t)tok * D_MODEL + t * 4) =
        (u16x4){f2bf(v.x * cv.x * r), f2bf(v.y * cv.y * r),
                f2bf(v.z * cv.z * r), f2bf(v.w * cv.w * r)};
}

// ---------------------------------------------------------------- tiled B^T GEMM (m97 structure)
template<int NT, int MODE>
__global__ __launch_bounds__(256) void gemm_bt(const u16* __restrict__ A, const u16* __restrict__ B,
                                               u16* __restrict__ Cq, u16* __restrict__ Ck,
                                               u16* __restrict__ Cv, float* __restrict__ Cf,
                                               const float* __restrict__ skip,
                                               int M, int N, int K) {
    __shared__ u16 As[128 * 32];
    __shared__ u16 Bs[NT * 32];
    constexpr int FN = NT / 32;                       // col frags per warp (128->4, 64->2)
    int tid = threadIdx.x;
    int lane = tid & 63, w = tid >> 6;
    int wr = w >> 1;
    int wc = w & 1;
    int m0 = blockIdx.x * 128, n0 = blockIdx.y * NT;
    f32x4 acc[4][FN] = {};
    const u16* Ag = A + (size_t)m0 * K;
    const u16* Bg = B + (size_t)n0 * K;
    int lr = lane & 15, lq = lane >> 4;

    for (int kt = 0; kt < K; kt += 32) {
        __syncthreads();
        #pragma unroll
        for (int i = 0; i < 2; ++i) {
            int c = i * 256 + tid;
            int row = c >> 2, col = c & 3;
            async16(Ag + (size_t)row * K + kt + col * 8, &As[c * 8]);
        }
        #pragma unroll
        for (int i = 0; i < NT / 64; ++i) {
            int c = i * 256 + tid;
            int row = c >> 2, col = c & 3;
            async16(Bg + (size_t)row * K + kt + col * 8, &Bs[c * 8]);
        }
        __syncthreads();
        bfrag af[4], bfv[FN];
        #pragma unroll
        for (int fm = 0; fm < 4; ++fm)
            af[fm] = *(const bfrag*)&As[(wr * 64 + fm * 16 + lr) * 32 + lq * 8];
        #pragma unroll
        for (int fn = 0; fn < FN; ++fn)
            bfv[fn] = *(const bfrag*)&Bs[(wc * (NT / 2) + fn * 16 + lr) * 32 + lq * 8];
        #pragma unroll
        for (int fm = 0; fm < 4; ++fm)
            #pragma unroll
            for (int fn = 0; fn < FN; ++fn)
                acc[fm][fn] = __builtin_amdgcn_mfma_f32_16x16x32_bf16(af[fm], bfv[fn], acc[fm][fn], 0, 0, 0);
    }

    #pragma unroll
    for (int fm = 0; fm < 4; ++fm)
        #pragma unroll
        for (int fn = 0; fn < FN; ++fn) {
            int rowbase = m0 + wr * 64 + fm * 16 + lq * 4;
            int colbase = n0 + wc * (NT / 2) + fn * 16;        // lane-invariant
            if (MODE == 1) {
                #pragma unroll
                for (int r = 0; r < 4; ++r) {
                    int row = rowbase + r, col = colbase + lr;
                    Cf[(size_t)row * N + col] = acc[fm][fn][r] + skip[(size_t)row * N + col];
                }
            } else {
                int sel = colbase >> 10;
                int h = (colbase >> 6) & 15;
                int bb = rowbase >> 11, s = rowbase & 2047;
                if (sel == 2) {
                    int e = (colbase & 63) + lr;
                    u16x4 pk = {f2bf(acc[fm][fn][0]), f2bf(acc[fm][fn][1]),
                                f2bf(acc[fm][fn][2]), f2bf(acc[fm][fn][3])};
                    *(u16x4*)&Cv[((size_t)(bb * N_HEADS + h) * D_HEAD + e) * SEQ + s] = pk;
                } else {
                    int e = (colbase & 63) + lr;
                    u16* p = sel ? Ck : Cq;
                    #pragma unroll
                    for (int r = 0; r < 4; ++r)
                        p[((size_t)(bb * N_HEADS + h) * SEQ + (s + r)) * D_HEAD + e] = f2bf(acc[fm][fn][r]);
                }
            }
        }
}

// ---------------------------------------------------------------- q/k: L2-normalize + RoPE (in place)
// q additionally pre-scaled by log2(e) so attention uses bare exp2.
__global__ __launch_bounds__(256) void postqk_kernel(u16* __restrict__ q, u16* __restrict__ k,
                                                     const float* __restrict__ pos,
                                                     const float* __restrict__ scale) {
    int tid = threadIdx.x, lane = tid & 63, w = tid >> 6;
    int wid = blockIdx.x * 4 + w;            // = bh*2048 + s
    int bh = wid >> 11, s = wid & 2047;
    int b = bh >> 4, h = bh & 15;
    size_t base = (size_t)wid * 64 + lane;
    float qv = bf2f(q[base]);
    float kv = bf2f(k[base]);
    float qs = qv * qv, ks = kv * kv;
    for (int m = 1; m < 64; m <<= 1) { qs += __shfl_xor(qs, m); ks += __shfl_xor(ks, m); }
    float sc = sqrtf(scale[h]);
    qv *= sc * 1.4426950408889634f * rsqrtf(qs + 1e-6f);   // fold log2(e) into q
    kv *= sc * rsqrtf(ks + 1e-6f);
    float qp = __shfl_xor(qv, 8);
    float kp = __shfl_xor(kv, 8);
    if (lane < 16) {
        int j = lane & 7;
        // freqs[h][j] = exp(log(pi) + (j*16+h)*ln(10)/128), fp64 to match np
        double lf = 1.1447298858494001741 + (double)(j * 16 + h) * (2.302585092994045684 / 128.0);
        float fr = (float)exp(lf);
        float th = pos[b * SEQ + s] * fr;
        float cth = cosf(th), sth = sinf(th);
        if (lane < 8) { qv = qv * cth - qp * sth; kv = kv * cth - kp * sth; }
        else          { qv = qv * cth + qp * sth; kv = kv * cth + kp * sth; }
    }
    q[base] = f2bf(qv);
    k[base] = f2bf(kv);
}

// ---------------------------------------------------------------- flash attention, split-KV, 8-wave
// q,k: (b,h,s,64) bf16 (q pre-scaled by log2e); vt: (b,h,64,s) bf16
// Block: 256 q-rows x 1024 kv (z). 8 waves x 32 rows. Double-buffered K/V with
// next-tile prefetch, one barrier per tile. P = exp2(s) (scores bounded, fixed max).
__global__ __launch_bounds__(512) void attn_kernel(const u16* __restrict__ q,
                                                   const u16* __restrict__ k,
                                                   const u16* __restrict__ vt,
                                                   u16* __restrict__ o_part,
                                                   float* __restrict__ lsum_part) {
    __shared__ u16 Ks[2][64 * 64];
    __shared__ u16 Vs[2][64 * 64];
    __shared__ u16 Ps[8][2][64 * 16];   // per-wave, per-mfrag col-major P plane [k=64][q=16]
    int tid = threadIdx.x, lane = tid & 63, w = tid >> 6;
    int bh = blockIdx.y;
    int qs = blockIdx.x * 256;
    int z = blockIdx.z;
    int kv0 = z * (SEQ / 2);
    int lr = lane & 15, lq = lane >> 4;

    bfrag qf[2][2];
    #pragma unroll
    for (int mf = 0; mf < 2; ++mf) {
        const u16* qb = q + ((size_t)bh * SEQ + qs + w * 32 + mf * 16 + lr) * D_HEAD + lq * 8;
        qf[mf][0] = *(const bfrag*)qb;
        qf[mf][1] = *(const bfrag*)(qb + 32);
    }
    bfrag ones;
    #pragma unroll
    for (int j = 0; j < 8; ++j) ones[j] = (__bf16)1.0f;

    f32x4 oacc[2][4] = {};
    f32x4 oacc5[2] = {};                 // row sums
    const u16* kbase = k + (size_t)bh * SEQ * D_HEAD;
    const u16* vbase = vt + (size_t)bh * D_HEAD * SEQ;
    u16* Pw = &Ps[w][0][0];

    // staging addresses: 512 threads cover one 64x64 K chunk + one V chunk (16B each)
    int srow = tid >> 3, scol = (tid & 7) ^ ((tid >> 3) & 7);   // pre-swizzled source
    const u16* kg = kbase + (size_t)srow * 64 + scol * 8;       // + kt*64 per tile
    const u16* vg = vbase + (size_t)srow * SEQ + scol * 8;      // + kt per tile

    #define STAGE(kt, buf) do { \
        async16(kg + (size_t)(kt) * 64, &Ks[buf][tid * 8]); \
        async16(vg + (kt),              &Vs[buf][tid * 8]); } while (0)

    STAGE(kv0, 0);
    asm volatile("s_waitcnt vmcnt(0)" ::: "memory");
    __syncthreads();

    const int NTILE = (SEQ / 2) / 64;   // 16
    for (int t = 0; t < NTILE; ++t) {
        int buf = t & 1;
        if (t + 1 < NTILE) STAGE(kv0 + (t + 1) * 64, buf ^ 1);
        const u16* Kb = Ks[buf];
        const u16* Vb = Vs[buf];

        // QK^T: D[i=q(16 of mf)][j=kv16(nb)]
        f32x4 sacc[2][4] = {};
        __builtin_amdgcn_s_setprio(1);
        #pragma unroll
        for (int nb = 0; nb < 4; ++nb) {
            int row = nb * 16 + lr;
            #pragma unroll
            for (int kb = 0; kb < 2; ++kb) {
                bfrag kf = *(const bfrag*)&Kb[row * 64 + (((kb * 4 + lq) ^ (row & 7)) * 8)];
                sacc[0][nb] = __builtin_amdgcn_mfma_f32_16x16x32_bf16(qf[0][kb], kf, sacc[0][nb], 0, 0, 0);
                sacc[1][nb] = __builtin_amdgcn_mfma_f32_16x16x32_bf16(qf[1][kb], kf, sacc[1][nb], 0, 0, 0);
            }
        }
        __builtin_amdgcn_s_setprio(0);

        // P = exp2(s); store col-major (packed b64)
        #pragma unroll
        for (int mf = 0; mf < 2; ++mf)
            #pragma unroll
            for (int nb = 0; nb < 4; ++nb) {
                float p0 = exp2f(sacc[mf][nb][0]);
                float p1 = exp2f(sacc[mf][nb][1]);
                float p2 = exp2f(sacc[mf][nb][2]);
                float p3 = exp2f(sacc[mf][nb][3]);
                bf16x4 pk = {(__bf16)p0, (__bf16)p1, (__bf16)p2, (__bf16)p3};
                *(bf16x4*)&Pw[mf * 1024 + (nb * 16 + lr) * 16 + lq * 4] = pk;
            }

        // transpose-read P back as PV A-fragments
        u16x4 pa[2][2][2];
        #pragma unroll
        for (int mf = 0; mf < 2; ++mf)
            #pragma unroll
            for (int kb = 0; kb < 2; ++kb) {
                const u16* pbase = &Pw[mf * 1024 + kb * 512 + lq * 128 + lr * 4];
                pa[mf][kb][0] = tr_read(pbase);
                pa[mf][kb][1] = tr_read(pbase + 64);
            }
        asm volatile("s_waitcnt lgkmcnt(0)" ::: "memory");
        __builtin_amdgcn_sched_barrier(0);

        // PV + ones row-sum
        __builtin_amdgcn_s_setprio(1);
        #pragma unroll
        for (int kb = 0; kb < 2; ++kb) {
            bfrag pf[2];
            #pragma unroll
            for (int mf = 0; mf < 2; ++mf) {
                u16x8 cat = __builtin_shufflevector(pa[mf][kb][0], pa[mf][kb][1], 0, 1, 2, 3, 4, 5, 6, 7);
                pf[mf] = __builtin_bit_cast(bfrag, cat);
            }
            oacc5[0] = __builtin_amdgcn_mfma_f32_16x16x32_bf16(pf[0], ones, oacc5[0], 0, 0, 0);
            oacc5[1] = __builtin_amdgcn_mfma_f32_16x16x32_bf16(pf[1], ones, oacc5[1], 0, 0, 0);
            #pragma unroll
            for (int eb = 0; eb < 4; ++eb) {
                int row = eb * 16 + lr;
                bfrag vf = *(const bfrag*)&Vb[row * 64 + (((kb * 4 + lq) ^ (row & 7)) * 8)];
                oacc[0][eb] = __builtin_amdgcn_mfma_f32_16x16x32_bf16(pf[0], vf, oacc[0][eb], 0, 0, 0);
                oacc[1][eb] = __builtin_amdgcn_mfma_f32_16x16x32_bf16(pf[1], vf, oacc[1][eb], 0, 0, 0);
            }
        }
        __builtin_amdgcn_s_setprio(0);

        asm volatile("s_waitcnt vmcnt(0)" ::: "memory");   // prefetched tile landed
        __syncthreads();
    }
    #undef STAGE

    int b = bh >> 4, h = bh & 15;
    u16* op = o_part + (size_t)z * NTOK * D_MODEL;
    #pragma unroll
    for (int mf = 0; mf < 2; ++mf) {
        #pragma unroll
        for (int r = 0; r < 4; ++r) {
            int qrow = qs + w * 32 + mf * 16 + lq * 4 + r;
            if (lr == 0)
                lsum_part[((size_t)z * BATCH * N_HEADS + bh) * SEQ + qrow] = oacc5[mf][r];
            #pragma unroll
            for (int eb = 0; eb < 4; ++eb) {
                int e = eb * 16 + lr;
                op[((size_t)b * SEQ + qrow) * D_MODEL + h * D_HEAD + e] = f2bf(oacc[mf][eb][r]);
            }
        }
    }
}

// ---------------------------------------------------------------- combine split-KV partials
__global__ __launch_bounds__(256) void combine_kernel(const u16* __restrict__ o_part,
                                                      const float* __restrict__ lsum_part,
                                                      u16* __restrict__ out) {
    int i = blockIdx.x * 256 + threadIdx.x;      // one per 8 elements
    int base = i * 8;
    int t = base >> 10, col = base & 1023;
    int b = t >> 11, s = t & 2047, h = col >> 6;
    size_t li = (size_t)(b * N_HEADS + h) * SEQ + s;
    float inv = 1.0f / (lsum_part[li] + lsum_part[li + (size_t)BATCH * N_HEADS * SEQ]);
    u16x8 a0 = *(const u16x8*)(o_part + base);
    u16x8 a1 = *(const u16x8*)(o_part + (size_t)NTOK * D_MODEL + base);
    u16x8 r;
    #pragma unroll
    for (int j = 0; j < 8; ++j) r[j] = f2bf((bf2f(a0[j]) + bf2f(a1[j])) * inv);
    *(u16x8*)(out + base) = r;
}

// ---------------------------------------------------------------- launcher
extern "C" void kernel_launch(void* const* d_in, const int* in_sizes, int n_in,
                              void* d_out, int out_size, void* d_ws, size_t ws_size,
                              hipStream_t stream) {
    const float* x      = (const float*)d_in[0];
    const float* pos    = (const float*)d_in[1];
    const float* cond   = (const float*)d_in[2];
    const float* w_norm = (const float*)d_in[3];
    const float* w_qkv  = (const float*)d_in[4];
    const float* scale  = (const float*)d_in[5];
    const float* w_out  = (const float*)d_in[6];
    float* out = (float*)d_out;

    char* ws = (char*)d_ws;
    u16* xn     = (u16*)ws;                               // 8 MB (aliased by attn_o later)
    u16* wqkv_b = (u16*)(ws + (8u  << 20));               // 6 MB
    u16* wout_b = (u16*)(ws + (14u << 20));               // 2 MB
    float* cs   = (float*)(ws + (16u << 20));             // 8 KB
    u16* qb     = (u16*)(ws + (16u << 20) + (1u << 16));  // 8 MB
    const size_t HSZ = (size_t)BATCH * N_HEADS * SEQ * D_HEAD;
    u16* kb = qb + HSZ;                                   // 8 MB
    u16* vt = kb + HSZ;                                   // 8 MB (written transposed by gemm)
    u16* o_part   = (u16*)(ws + (41u << 20));             // 2 x 8 MB bf16 partials
    float* lsum_p = (float*)(ws + (57u << 20));           // 2 x 256 KB
    u16* attn_o = xn;                                     // alias: xn dead after QKV GEMM

    prep_kernel<<<dim3(2560), dim3(256), 0, stream>>>(w_qkv, w_out, wqkv_b, wout_b, cond, w_norm, cs);
    rmsnorm_kernel<<<dim3(NTOK), dim3(256), 0, stream>>>(x, cs, xn);
    gemm_bt<128, 0><<<dim3(NTOK / 128, QKV_N / 128), dim3(256), 0, stream>>>(
        xn, wqkv_b, qb, kb, vt, (float*)nullptr, (const float*)nullptr,
        NTOK, QKV_N, D_MODEL);
    postqk_kernel<<<dim3(BATCH * N_HEADS * SEQ / 4), dim3(256), 0, stream>>>(qb, kb, pos, scale);
    attn_kernel<<<dim3(SEQ / 256, BATCH * N_HEADS, 2), dim3(512), 0, stream>>>(
        qb, kb, vt, o_part, lsum_p);
    combine_kernel<<<dim3(NTOK * D_MODEL / 8 / 256), dim3(256), 0, stream>>>(o_part, lsum_p, attn_o);
    gemm_bt<64, 1><<<dim3(NTOK / 128, D_MODEL / 64), dim3(256), 0, stream>>>(
        attn_o, wout_b, nullptr, nullptr, nullptr, out, x,
        NTOK, D_MODEL, D_MODEL);
}